// Round 1
// baseline (352.557 us; speedup 1.0000x reference)
//
#include <hip/hip_runtime.h>

// MultiHeadSelfAttention: BS=4, S=2048, DIM=768, H=12, DH=64
// Pipeline: convert weights -> QKV proj (bf16 MFMA) -> flash attention -> O proj.
// All MFMA layouts per learn_hip m89/m91 verified mappings:
//   A-frag: A[m=lane&15][k=quad*8+j], B-frag: B[n=lane&15][k=quad*8+j]
//   C/D:    col=lane&15, row=quad*4+reg

#define BSZ 4
#define SEQ 2048
#define DIMD 768
#define NHD 12
#define DHD 64
#define MTOT (BSZ*SEQ)      // 8192
#define WELEM (DIMD*DIMD)   // 589824

typedef __bf16 bf16;
typedef __attribute__((ext_vector_type(8))) __bf16 bf16x8;
typedef __attribute__((ext_vector_type(4))) __bf16 bf16x4;
typedef __attribute__((ext_vector_type(4))) float f32x4;

__device__ __forceinline__ f32x4 mfma_bf16(bf16x8 a, bf16x8 b, f32x4 c) {
    return __builtin_amdgcn_mfma_f32_16x16x32_bf16(a, b, c, 0, 0, 0);
}

// ---------------- weight fp32 -> bf16 ----------------
__global__ __launch_bounds__(256) void convert_w_kernel(
    const float* __restrict__ w0, const float* __restrict__ w1,
    const float* __restrict__ w2, const float* __restrict__ w3,
    bf16* __restrict__ out) {
    const int z = blockIdx.y;
    const float* src = (z == 0) ? w0 : (z == 1) ? w1 : (z == 2) ? w2 : w3;
    const int i = (blockIdx.x * 256 + threadIdx.x) * 4;
    float4 v = *(const float4*)(src + i);
    bf16x4 o;
    o[0] = (bf16)v.x; o[1] = (bf16)v.y; o[2] = (bf16)v.z; o[3] = (bf16)v.w;
    *(bf16x4*)(out + (size_t)z * WELEM + i) = o;
}

// ---------------- QKV projection: X(fp32) @ W^T + b -> bf16 ----------------
// grid: (M/64, N/64, 3)  z: 0=Q (scaled 1/8, layout [b][h][s][dh])
//                           1=K (layout [b][h][s][dh])
//                           2=V (layout [b][h][dh][s]  -- transposed)
__global__ __launch_bounds__(256) void proj_kernel(
    const float* __restrict__ xq, const float* __restrict__ xk, const float* __restrict__ xv,
    const bf16* __restrict__ wall,
    const float* __restrict__ bq, const float* __restrict__ bk, const float* __restrict__ bv,
    bf16* __restrict__ Qb, bf16* __restrict__ Kb, bf16* __restrict__ Vb) {
    __shared__ __align__(16) bf16 As[64][72];   // +8 pad keeps 16B align (144B stride)
    __shared__ __align__(16) bf16 Bs[64][72];
    const int tid = threadIdx.x;
    const int z = blockIdx.z;
    const float* A    = (z == 0) ? xq : (z == 1) ? xk : xv;
    const bf16*  W    = wall + (size_t)z * WELEM;
    const float* bias = (z == 0) ? bq : (z == 1) ? bk : bv;
    const float scale = (z == 0) ? 0.125f : 1.0f;
    const int m0 = blockIdx.x * 64, n0 = blockIdx.y * 64;
    const int lane = tid & 63, wv = tid >> 6;
    const int quad = lane >> 4, l16 = lane & 15;
    const int wr = wv >> 1, wc = wv & 1;
    const int srow = tid >> 2, scol = (tid & 3) * 16;

    f32x4 acc[2][2] = {};
    for (int kt = 0; kt < DIMD / 64; ++kt) {
        const float* ap = A + (size_t)(m0 + srow) * DIMD + kt * 64 + scol;
        float4 a0 = *(const float4*)ap;
        float4 a1 = *(const float4*)(ap + 4);
        float4 a2 = *(const float4*)(ap + 8);
        float4 a3 = *(const float4*)(ap + 12);
        const bf16* bp = W + (size_t)(n0 + srow) * DIMD + kt * 64 + scol;
        bf16x8 b0 = *(const bf16x8*)bp;
        bf16x8 b1 = *(const bf16x8*)(bp + 8);
        if (kt) __syncthreads();            // prior MFMA reads done
        bf16x8 c0, c1;
        c0[0] = (bf16)a0.x; c0[1] = (bf16)a0.y; c0[2] = (bf16)a0.z; c0[3] = (bf16)a0.w;
        c0[4] = (bf16)a1.x; c0[5] = (bf16)a1.y; c0[6] = (bf16)a1.z; c0[7] = (bf16)a1.w;
        c1[0] = (bf16)a2.x; c1[1] = (bf16)a2.y; c1[2] = (bf16)a2.z; c1[3] = (bf16)a2.w;
        c1[4] = (bf16)a3.x; c1[5] = (bf16)a3.y; c1[6] = (bf16)a3.z; c1[7] = (bf16)a3.w;
        *(bf16x8*)&As[srow][scol]     = c0;
        *(bf16x8*)&As[srow][scol + 8] = c1;
        *(bf16x8*)&Bs[srow][scol]     = b0;
        *(bf16x8*)&Bs[srow][scol + 8] = b1;
        __syncthreads();
        for (int ks = 0; ks < 64; ks += 32) {
            bf16x8 af0 = *(const bf16x8*)&As[wr * 32 + l16][ks + quad * 8];
            bf16x8 af1 = *(const bf16x8*)&As[wr * 32 + 16 + l16][ks + quad * 8];
            bf16x8 bf0 = *(const bf16x8*)&Bs[wc * 32 + l16][ks + quad * 8];
            bf16x8 bf1 = *(const bf16x8*)&Bs[wc * 32 + 16 + l16][ks + quad * 8];
            acc[0][0] = mfma_bf16(af0, bf0, acc[0][0]);
            acc[0][1] = mfma_bf16(af0, bf1, acc[0][1]);
            acc[1][0] = mfma_bf16(af1, bf0, acc[1][0]);
            acc[1][1] = mfma_bf16(af1, bf1, acc[1][1]);
        }
    }
    const int mb = m0 >> 11;        // batch index (block never spans batches)
    const int sbase = m0 & 2047;
    for (int ti = 0; ti < 2; ++ti)
        for (int tj = 0; tj < 2; ++tj) {
            f32x4 a = acc[ti][tj];
            const int n = n0 + wc * 32 + tj * 16 + l16;
            const int h = n >> 6, dh = n & 63;
            const float bvl = bias[n];
            const int mloc = wr * 32 + ti * 16 + quad * 4;
            if (z < 2) {
                bf16* outp = (z == 0) ? Qb : Kb;
                const size_t base = (size_t)(mb * NHD + h) * SEQ;
                for (int r = 0; r < 4; ++r) {
                    const int s = sbase + mloc + r;
                    outp[(base + s) * 64 + dh] = (bf16)((a[r] + bvl) * scale);
                }
            } else {
                const int s = sbase + mloc;
                bf16x4 pk;
                for (int r = 0; r < 4; ++r) pk[r] = (bf16)(a[r] + bvl);
                *(bf16x4*)&Vb[((size_t)(mb * NHD + h) * 64 + dh) * SEQ + s] = pk;
            }
        }
}

// ---------------- flash attention ----------------
// grid: (SEQ/64, H, BS), block 256 (4 waves).
// Phase 1: S^T = K·Q^T (A=K, B=Q), per-query online softmax, P -> LDS [q][key].
// Phase 2: O^T = V^T·P^T (A=Vts, B=Ps). Output ctx[b][s][h*64+dh] bf16.
__global__ __launch_bounds__(256) void attn_kernel(
    const bf16* __restrict__ Qb, const bf16* __restrict__ Kb, const bf16* __restrict__ Vb,
    const int* __restrict__ mask, bf16* __restrict__ CTX) {
    __shared__ __align__(16) bf16 Qs[64][72];
    __shared__ __align__(16) bf16 Ks[64][72];
    __shared__ __align__(16) bf16 Vts[64][72];
    __shared__ __align__(16) bf16 Ps[64][72];
    __shared__ float sadd[64];
    __shared__ float alphas[64];
    __shared__ float invs[64];
    const int tid = threadIdx.x;
    const int b = blockIdx.z, h = blockIdx.y, qt = blockIdx.x;
    const int bh = b * NHD + h;
    const int lane = tid & 63, wv = tid >> 6, quad = lane >> 4, l16 = lane & 15;
    const int srow = tid >> 2, scol = (tid & 3) * 16;
    const bf16* Qp = Qb + ((size_t)bh * SEQ + qt * 64) * 64;
    const bf16* Kp = Kb + (size_t)bh * SEQ * 64;
    const bf16* Vp = Vb + (size_t)bh * 64 * SEQ;
    {
        const bf16* qp = Qp + (size_t)srow * 64 + scol;
        *(bf16x8*)&Qs[srow][scol]     = *(const bf16x8*)qp;
        *(bf16x8*)&Qs[srow][scol + 8] = *(const bf16x8*)(qp + 8);
    }
    f32x4 acc_o[4] = {};
    float row_max = -1e30f, row_sum = 0.f;
    for (int kt = 0; kt < SEQ / 64; ++kt) {
        const int k0 = kt * 64;
        const bf16* kp = Kp + (size_t)(k0 + srow) * 64 + scol;
        bf16x8 kr0 = *(const bf16x8*)kp;
        bf16x8 kr1 = *(const bf16x8*)(kp + 8);
        const bf16* vp = Vp + (size_t)srow * SEQ + k0 + scol;
        bf16x8 vr0 = *(const bf16x8*)vp;
        bf16x8 vr1 = *(const bf16x8*)(vp + 8);
        float ma = 0.f;
        if (tid < 64) ma = (mask[b * SEQ + k0 + tid] == 0) ? -1e30f : 0.f;
        __syncthreads();                       // (A) prev phase-2 reads done
        *(bf16x8*)&Ks[srow][scol]      = kr0;
        *(bf16x8*)&Ks[srow][scol + 8]  = kr1;
        *(bf16x8*)&Vts[srow][scol]     = vr0;
        *(bf16x8*)&Vts[srow][scol + 8] = vr1;
        if (tid < 64) sadd[tid] = ma;
        __syncthreads();                       // (B) staging visible
        // phase 1: S^T tiles for this wave's 16 queries
        bf16x8 qf0 = *(const bf16x8*)&Qs[wv * 16 + l16][quad * 8];
        bf16x8 qf1 = *(const bf16x8*)&Qs[wv * 16 + l16][32 + quad * 8];
        f32x4 st[4];
        for (int jj = 0; jj < 4; ++jj) {
            bf16x8 kf0 = *(const bf16x8*)&Ks[jj * 16 + l16][quad * 8];
            bf16x8 kf1 = *(const bf16x8*)&Ks[jj * 16 + l16][32 + quad * 8];
            f32x4 zf = {};
            f32x4 t = mfma_bf16(kf0, qf0, zf);
            st[jj] = mfma_bf16(kf1, qf1, t);
        }
        float tmax = -1e30f;
        for (int jj = 0; jj < 4; ++jj)
            for (int r = 0; r < 4; ++r) {
                st[jj][r] += sadd[jj * 16 + quad * 4 + r];
                tmax = fmaxf(tmax, st[jj][r]);
            }
        tmax = fmaxf(tmax, __shfl_xor(tmax, 16));
        tmax = fmaxf(tmax, __shfl_xor(tmax, 32));
        const float nmax = fmaxf(row_max, tmax);
        const float alpha = __expf(row_max - nmax);
        float tsum = 0.f;
        for (int jj = 0; jj < 4; ++jj) {
            bf16x4 pk;
            for (int r = 0; r < 4; ++r) {
                const float p = __expf(st[jj][r] - nmax);
                tsum += p;
                pk[r] = (bf16)p;
            }
            *(bf16x4*)&Ps[wv * 16 + l16][jj * 16 + quad * 4] = pk;
        }
        tsum += __shfl_xor(tsum, 16);
        tsum += __shfl_xor(tsum, 32);
        row_sum = row_sum * alpha + tsum;
        row_max = nmax;
        if (lane < 16) alphas[wv * 16 + lane] = alpha;
        __syncthreads();                       // (C) Ps/alphas visible
        // phase 2: O^T += V^T · P^T  (this wave owns dh strip wv*16..+16)
        bf16x8 vf0 = *(const bf16x8*)&Vts[wv * 16 + l16][quad * 8];
        bf16x8 vf1 = *(const bf16x8*)&Vts[wv * 16 + l16][32 + quad * 8];
        for (int qj = 0; qj < 4; ++qj) {
            const float al = alphas[qj * 16 + l16];
            f32x4 c = acc_o[qj];
            for (int r = 0; r < 4; ++r) c[r] *= al;
            bf16x8 pf0 = *(const bf16x8*)&Ps[qj * 16 + l16][quad * 8];
            bf16x8 pf1 = *(const bf16x8*)&Ps[qj * 16 + l16][32 + quad * 8];
            c = mfma_bf16(vf0, pf0, c);
            c = mfma_bf16(vf1, pf1, c);
            acc_o[qj] = c;
        }
    }
    if (lane < 16) invs[wv * 16 + lane] = 1.0f / row_sum;
    __syncthreads();
    for (int qj = 0; qj < 4; ++qj) {
        const float inv = invs[qj * 16 + l16];
        bf16x4 pk;
        for (int r = 0; r < 4; ++r) pk[r] = (bf16)(acc_o[qj][r] * inv);
        const int s = qt * 64 + qj * 16 + l16;
        *(bf16x4*)&CTX[(size_t)(b * SEQ + s) * DIMD + h * 64 + wv * 16 + quad * 4] = pk;
    }
}

// ---------------- output projection: CTX(bf16) @ Wo^T + b -> fp32 ----------------
__global__ __launch_bounds__(256) void oproj_kernel(
    const bf16* __restrict__ ctx, const bf16* __restrict__ wo,
    const float* __restrict__ bo, float* __restrict__ out) {
    __shared__ __align__(16) bf16 As[64][72];
    __shared__ __align__(16) bf16 Bs[64][72];
    const int tid = threadIdx.x;
    const int m0 = blockIdx.x * 64, n0 = blockIdx.y * 64;
    const int lane = tid & 63, wv = tid >> 6;
    const int quad = lane >> 4, l16 = lane & 15;
    const int wr = wv >> 1, wc = wv & 1;
    const int srow = tid >> 2, scol = (tid & 3) * 16;

    f32x4 acc[2][2] = {};
    for (int kt = 0; kt < DIMD / 64; ++kt) {
        const bf16* ap = ctx + (size_t)(m0 + srow) * DIMD + kt * 64 + scol;
        bf16x8 a0 = *(const bf16x8*)ap;
        bf16x8 a1 = *(const bf16x8*)(ap + 8);
        const bf16* bp = wo + (size_t)(n0 + srow) * DIMD + kt * 64 + scol;
        bf16x8 b0 = *(const bf16x8*)bp;
        bf16x8 b1 = *(const bf16x8*)(bp + 8);
        if (kt) __syncthreads();
        *(bf16x8*)&As[srow][scol]     = a0;
        *(bf16x8*)&As[srow][scol + 8] = a1;
        *(bf16x8*)&Bs[srow][scol]     = b0;
        *(bf16x8*)&Bs[srow][scol + 8] = b1;
        __syncthreads();
        for (int ks = 0; ks < 64; ks += 32) {
            bf16x8 af0 = *(const bf16x8*)&As[wr * 32 + l16][ks + quad * 8];
            bf16x8 af1 = *(const bf16x8*)&As[wr * 32 + 16 + l16][ks + quad * 8];
            bf16x8 bf0 = *(const bf16x8*)&Bs[wc * 32 + l16][ks + quad * 8];
            bf16x8 bf1 = *(const bf16x8*)&Bs[wc * 32 + 16 + l16][ks + quad * 8];
            acc[0][0] = mfma_bf16(af0, bf0, acc[0][0]);
            acc[0][1] = mfma_bf16(af0, bf1, acc[0][1]);
            acc[1][0] = mfma_bf16(af1, bf0, acc[1][0]);
            acc[1][1] = mfma_bf16(af1, bf1, acc[1][1]);
        }
    }
    for (int ti = 0; ti < 2; ++ti)
        for (int tj = 0; tj < 2; ++tj) {
            f32x4 a = acc[ti][tj];
            const int n = n0 + wc * 32 + tj * 16 + l16;
            const float bvl = bo[n];
            const int mloc = wr * 32 + ti * 16 + quad * 4;
            for (int r = 0; r < 4; ++r)
                out[(size_t)(m0 + mloc + r) * DIMD + n] = a[r] + bvl;
        }
}

extern "C" void kernel_launch(void* const* d_in, const int* in_sizes, int n_in,
                              void* d_out, int out_size, void* d_ws, size_t ws_size,
                              hipStream_t stream) {
    const float* query = (const float*)d_in[0];
    const float* key_t = (const float*)d_in[1];
    const float* value = (const float*)d_in[2];
    const int*   mask  = (const int*)d_in[3];
    const float* q_w = (const float*)d_in[4];
    const float* q_b = (const float*)d_in[5];
    const float* k_w = (const float*)d_in[6];
    const float* k_b = (const float*)d_in[7];
    const float* v_w = (const float*)d_in[8];
    const float* v_b = (const float*)d_in[9];
    const float* o_w = (const float*)d_in[10];
    const float* o_b = (const float*)d_in[11];
    float* out = (float*)d_out;

    bf16* ws  = (bf16*)d_ws;
    bf16* W   = ws;                                  // 4*589824 bf16
    bf16* Qb  = ws + (size_t)4 * WELEM;              // [b][h][s][dh]
    bf16* Kb  = Qb + (size_t)MTOT * DIMD;            // [b][h][s][dh]
    bf16* Vb  = Kb + (size_t)MTOT * DIMD;            // [b][h][dh][s]
    bf16* CTX = Vb + (size_t)MTOT * DIMD;            // [b*s][dim]

    convert_w_kernel<<<dim3(WELEM / 1024, 4), 256, 0, stream>>>(q_w, k_w, v_w, o_w, W);
    proj_kernel<<<dim3(MTOT / 64, DIMD / 64, 3), 256, 0, stream>>>(
        query, key_t, value, W, q_b, k_b, v_b, Qb, Kb, Vb);
    attn_kernel<<<dim3(SEQ / 64, NHD, BSZ), 256, 0, stream>>>(Qb, Kb, Vb, mask, CTX);
    oproj_kernel<<<dim3(MTOT / 64, DIMD / 64), 256, 0, stream>>>(
        CTX, W + (size_t)3 * WELEM, o_b, out);
}

// Round 2
// 329.283 us; speedup vs baseline: 1.0707x; 1.0707x over previous
//
#include <hip/hip_runtime.h>

// MultiHeadSelfAttention: BS=4, S=2048, DIM=768, H=12, DH=64
// R2: m97-style 128x128 GEMM (global_load_lds w16 + XOR swizzle) for projections,
//     flash attention with direct-global K/V fragments + double-buffered P (1 barrier/iter).
// MFMA layouts (learn_hip m89/m91): A/B-frag: [m|n = lane&15][k = quad*8+j]
//                                   C/D: col = lane&15, row = quad*4 + reg

#define BSZ 4
#define SEQ 2048
#define DIMD 768
#define NHD 12
#define MTOT (BSZ*SEQ)      // 8192
#define WELEM (DIMD*DIMD)   // 589824

typedef __bf16 bf16;
typedef __attribute__((ext_vector_type(8))) __bf16 bf16x8;
typedef __attribute__((ext_vector_type(4))) __bf16 bf16x4;
typedef __attribute__((ext_vector_type(4))) float f32x4;

__device__ __forceinline__ f32x4 mfma_bf16(bf16x8 a, bf16x8 b, f32x4 c) {
    return __builtin_amdgcn_mfma_f32_16x16x32_bf16(a, b, c, 0, 0, 0);
}

__device__ __forceinline__ void async16(const bf16* g, bf16* l) {
    __builtin_amdgcn_global_load_lds(
        (const __attribute__((address_space(1))) unsigned int*)g,
        (__attribute__((address_space(3))) unsigned int*)l, 16, 0, 0);
}

// ---------------- converts ----------------
__global__ __launch_bounds__(256) void convert_w_kernel(
    const float* __restrict__ w0, const float* __restrict__ w1,
    const float* __restrict__ w2, const float* __restrict__ w3,
    bf16* __restrict__ out) {
    const int z = blockIdx.y;
    const float* src = (z == 0) ? w0 : (z == 1) ? w1 : (z == 2) ? w2 : w3;
    const int i = (blockIdx.x * 256 + threadIdx.x) * 4;
    float4 v = *(const float4*)(src + i);
    bf16x4 o;
    o[0] = (bf16)v.x; o[1] = (bf16)v.y; o[2] = (bf16)v.z; o[3] = (bf16)v.w;
    *(bf16x4*)(out + (size_t)z * WELEM + i) = o;
}

__global__ __launch_bounds__(256) void convert_x_kernel(
    const float* __restrict__ src, bf16* __restrict__ dst) {
    const int i = (blockIdx.x * 256 + threadIdx.x) * 4;
    float4 v = *(const float4*)(src + i);
    bf16x4 o;
    o[0] = (bf16)v.x; o[1] = (bf16)v.y; o[2] = (bf16)v.z; o[3] = (bf16)v.w;
    *(bf16x4*)(dst + i) = o;
}

// ---------------- shared 128x128xK768 GEMM core ----------------
// D[m][n] = sum_k A[m][k]*B[n][k], A/B row-major K-contiguous, K=768.
// LDS tiles 128x64 bf16, unpadded rows (128B) with XOR-8 column-block swizzle.
__device__ __forceinline__ void gemm_core_768(
    const bf16* __restrict__ Ag, const bf16* __restrict__ Bg,
    int m0, int n0, bf16* As, bf16* Bs, f32x4 (&acc)[4][4]) {
    const int tid = threadIdx.x;
    const int lane = tid & 63, wv = tid >> 6;
    const int quad = lane >> 4, l16 = lane & 15;
    const int wr = wv >> 1, wc = wv & 1;
    const int rr = lane >> 3, cbl = lane & 7;
    const int swz = l16 & 7;
    for (int kt = 0; kt < 12; ++kt) {
        if (kt) __syncthreads();                  // prior frag reads done
        for (int c = 0; c < 4; ++c) {
            const int row = c * 32 + wv * 8 + rr;
            const int cb = cbl ^ (row & 7);       // swizzled source col-block
            const size_t gcol = (size_t)kt * 64 + cb * 8;
            async16(Ag + (size_t)(m0 + row) * 768 + gcol, As + row * 64 + cbl * 8);
            async16(Bg + (size_t)(n0 + row) * 768 + gcol, Bs + row * 64 + cbl * 8);
        }
        __syncthreads();                          // drains vmcnt, LDS visible
        for (int ks = 0; ks < 2; ++ks) {
            bf16x8 af[4], bfr[4];
            for (int t = 0; t < 4; ++t)
                af[t] = *(const bf16x8*)(As + (wr * 64 + t * 16 + l16) * 64 +
                                         (((ks * 4 + quad) ^ swz) * 8));
            for (int t = 0; t < 4; ++t)
                bfr[t] = *(const bf16x8*)(Bs + (wc * 64 + t * 16 + l16) * 64 +
                                          (((ks * 4 + quad) ^ swz) * 8));
            for (int ti = 0; ti < 4; ++ti)
                for (int tj = 0; tj < 4; ++tj)
                    acc[ti][tj] = mfma_bf16(af[ti], bfr[tj], acc[ti][tj]);
        }
    }
}

// ---------------- QKV projection ----------------
// z<2 (Q,K): swapped operands (A=W m=feat 768, B=X n=rows 8192) -> out [b][h][s][dh]
// z=2 (V):   A=X (m=rows), B=W (n=feat)                         -> out [b][h][dh][s]
// grid (64, 6)
__global__ __launch_bounds__(256, 3) void proj_kernel(
    const bf16* __restrict__ X, const bf16* __restrict__ W,
    const float* __restrict__ bias, bf16* __restrict__ Out, int z) {
    __shared__ __align__(16) bf16 smem[2 * 128 * 64];
    bf16* As = smem;
    bf16* Bs = smem + 128 * 64;
    const int tid = threadIdx.x;
    const int lane = tid & 63, wv = tid >> 6;
    const int quad = lane >> 4, l16 = lane & 15;
    const int wr = wv >> 1, wc = wv & 1;
    f32x4 acc[4][4] = {};
    int m0, n0;
    const bf16 *Ag, *Bg;
    if (z < 2) { m0 = blockIdx.y * 128; n0 = blockIdx.x * 128; Ag = W; Bg = X; }
    else       { m0 = blockIdx.x * 128; n0 = blockIdx.y * 128; Ag = X; Bg = W; }
    gemm_core_768(Ag, Bg, m0, n0, As, Bs, acc);
    __syncthreads();                              // As/Bs reads done; reuse as Ot
    bf16* Ot = smem;                              // 128x128 bf16 tile
    if (z < 2) {
        const float scale = (z == 0) ? 0.125f : 1.0f;
        for (int ti = 0; ti < 4; ++ti) {
            const int featl = wr * 64 + ti * 16 + quad * 4;
            const float4 b4 = *(const float4*)(bias + m0 + featl);
            for (int tj = 0; tj < 4; ++tj) {
                const int sl = wc * 64 + tj * 16 + l16;
                bf16x4 pk;
                pk[0] = (bf16)((acc[ti][tj][0] + b4.x) * scale);
                pk[1] = (bf16)((acc[ti][tj][1] + b4.y) * scale);
                pk[2] = (bf16)((acc[ti][tj][2] + b4.z) * scale);
                pk[3] = (bf16)((acc[ti][tj][3] + b4.w) * scale);
                *(bf16x4*)&Ot[sl * 128 + featl] = pk;   // Ot[s][feat]
            }
        }
        __syncthreads();
        for (int it = 0; it < 8; ++it) {
            const int unit = it * 256 + tid;      // 16B units of the tile
            const int s = unit >> 4, u = unit & 15;
            const int feat = m0 + u * 8;
            const int hh = feat >> 6, dh = feat & 63;
            const int srow = n0 + s;
            const int bb = srow >> 11, s2 = srow & 2047;
            *(bf16x8*)&Out[((size_t)(bb * NHD + hh) * SEQ + s2) * 64 + dh] =
                *(const bf16x8*)&Ot[s * 128 + u * 8];
        }
    } else {
        for (int ti = 0; ti < 4; ++ti) {
            const int sl = wr * 64 + ti * 16 + quad * 4;
            for (int tj = 0; tj < 4; ++tj) {
                const int featl = wc * 64 + tj * 16 + l16;
                const float bv = bias[n0 + featl];
                bf16x4 pk;
                pk[0] = (bf16)(acc[ti][tj][0] + bv);
                pk[1] = (bf16)(acc[ti][tj][1] + bv);
                pk[2] = (bf16)(acc[ti][tj][2] + bv);
                pk[3] = (bf16)(acc[ti][tj][3] + bv);
                *(bf16x4*)&Ot[featl * 128 + sl] = pk;   // Ot[feat][s]
            }
        }
        __syncthreads();
        const int bb = m0 >> 11, sbase = m0 & 2047;
        for (int it = 0; it < 8; ++it) {
            const int unit = it * 256 + tid;
            const int fl = unit >> 4, u = unit & 15;
            const int feat = n0 + fl;
            const int hh = feat >> 6, dh = feat & 63;
            *(bf16x8*)&Out[((size_t)(bb * NHD + hh) * 64 + dh) * SEQ + sbase + u * 8] =
                *(const bf16x8*)&Ot[fl * 128 + u * 8];
        }
    }
}

// ---------------- flash attention ----------------
// grid (SEQ/128=16, 12, 4), block 256. Q-tile 128 (each wave owns 32 queries, 2 strips).
// Phase 1: S^T = K.Q^T with K frags direct from global; online softmax; P -> LDS (dbuf).
// Phase 2: O^T += V^T.P^T with V^T frags direct from global. 1 barrier per KV tile.
__global__ __launch_bounds__(256, 3) void attn_kernel(
    const bf16* __restrict__ Qb, const bf16* __restrict__ Kb, const bf16* __restrict__ Vb,
    const int* __restrict__ mask, bf16* __restrict__ CTX) {
    __shared__ __align__(16) bf16 Ps[2][128][72];
    __shared__ float alphas[2][128];
    __shared__ float sadd[2048];
    __shared__ float invs[128];
    __shared__ int anyz_s;
    const int tid = threadIdx.x;
    const int lane = tid & 63, wv = tid >> 6, quad = lane >> 4, l16 = lane & 15;
    const int b = blockIdx.z, h = blockIdx.y, qt = blockIdx.x;
    const int bh = b * NHD + h;
    if (tid == 0) anyz_s = 0;
    __syncthreads();
    {
        int4 m0v = *(const int4*)(mask + b * SEQ + tid * 8);
        int4 m1v = *(const int4*)(mask + b * SEQ + tid * 8 + 4);
        float4 f0, f1;
        f0.x = m0v.x ? 0.f : -1e30f; f0.y = m0v.y ? 0.f : -1e30f;
        f0.z = m0v.z ? 0.f : -1e30f; f0.w = m0v.w ? 0.f : -1e30f;
        f1.x = m1v.x ? 0.f : -1e30f; f1.y = m1v.y ? 0.f : -1e30f;
        f1.z = m1v.z ? 0.f : -1e30f; f1.w = m1v.w ? 0.f : -1e30f;
        *(float4*)&sadd[tid * 8] = f0;
        *(float4*)&sadd[tid * 8 + 4] = f1;
        if (!(m0v.x && m0v.y && m0v.z && m0v.w && m1v.x && m1v.y && m1v.z && m1v.w))
            anyz_s = 1;
    }
    // loop-invariant Q fragments (B operand), 2 strips of 16 queries
    bf16x8 qf0[2], qf1[2];
    for (int st = 0; st < 2; ++st) {
        const bf16* qp = Qb + ((size_t)bh * SEQ + qt * 128 + wv * 32 + st * 16 + l16) * 64;
        qf0[st] = *(const bf16x8*)(qp + quad * 8);
        qf1[st] = *(const bf16x8*)(qp + 32 + quad * 8);
    }
    const bf16* Kp = Kb + (size_t)bh * SEQ * 64 + (size_t)l16 * 64 + quad * 8;
    const bf16* Vp = Vb + (size_t)bh * 64 * SEQ + (size_t)(wv * 16 + l16) * SEQ + quad * 8;
    f32x4 acc_o[8] = {};
    float rm[2] = {-1e30f, -1e30f}, rs[2] = {0.f, 0.f};
    __syncthreads();
    const int az = anyz_s;
    for (int kt = 0; kt < SEQ / 64; ++kt) {
        const int buf = kt & 1, k0 = kt * 64;
        // K fragments direct from global (A operand: m=key, k=dh)
        bf16x8 kf0[4], kf1[4];
        for (int jj = 0; jj < 4; ++jj) {
            const bf16* kp = Kp + (size_t)(k0 + jj * 16) * 64;
            kf0[jj] = *(const bf16x8*)kp;
            kf1[jj] = *(const bf16x8*)(kp + 32);
        }
        f32x4 sc[2][4];
        for (int st = 0; st < 2; ++st)
            for (int jj = 0; jj < 4; ++jj) {
                f32x4 zf = {};
                zf = mfma_bf16(kf0[jj], qf0[st], zf);
                sc[st][jj] = mfma_bf16(kf1[jj], qf1[st], zf);
            }
        if (az)
            for (int jj = 0; jj < 4; ++jj) {
                const float4 sa = *(const float4*)&sadd[k0 + jj * 16 + quad * 4];
                for (int st = 0; st < 2; ++st) {
                    sc[st][jj][0] += sa.x; sc[st][jj][1] += sa.y;
                    sc[st][jj][2] += sa.z; sc[st][jj][3] += sa.w;
                }
            }
        for (int st = 0; st < 2; ++st) {
            float tmax = -1e30f;
            for (int jj = 0; jj < 4; ++jj)
                for (int r = 0; r < 4; ++r) tmax = fmaxf(tmax, sc[st][jj][r]);
            tmax = fmaxf(tmax, __shfl_xor(tmax, 16));
            tmax = fmaxf(tmax, __shfl_xor(tmax, 32));
            const float nmax = fmaxf(rm[st], tmax);
            const float alpha = __expf(rm[st] - nmax);
            rm[st] = nmax;
            float tsum = 0.f;
            for (int jj = 0; jj < 4; ++jj) {
                bf16x4 pk;
                for (int r = 0; r < 4; ++r) {
                    const float p = __expf(sc[st][jj][r] - nmax);
                    tsum += p;
                    pk[r] = (bf16)p;
                }
                *(bf16x4*)&Ps[buf][wv * 32 + st * 16 + l16][jj * 16 + quad * 4] = pk;
            }
            tsum += __shfl_xor(tsum, 16);
            tsum += __shfl_xor(tsum, 32);
            rs[st] = rs[st] * alpha + tsum;
            if (lane < 16) alphas[buf][wv * 32 + st * 16 + lane] = alpha;
        }
        // V^T fragments direct from global (A operand: m=dh, k=key)
        bf16x8 vf0 = *(const bf16x8*)(Vp + k0);
        bf16x8 vf1 = *(const bf16x8*)(Vp + k0 + 32);
        __syncthreads();                         // Ps/alphas[buf] visible
        for (int qj = 0; qj < 8; ++qj) {
            const float al = alphas[buf][qj * 16 + l16];
            f32x4 c = acc_o[qj];
            c[0] *= al; c[1] *= al; c[2] *= al; c[3] *= al;
            bf16x8 pf0 = *(const bf16x8*)&Ps[buf][qj * 16 + l16][quad * 8];
            bf16x8 pf1 = *(const bf16x8*)&Ps[buf][qj * 16 + l16][32 + quad * 8];
            c = mfma_bf16(vf0, pf0, c);
            c = mfma_bf16(vf1, pf1, c);
            acc_o[qj] = c;
        }
    }
    if (lane < 16) {
        invs[wv * 32 + lane] = 1.0f / rs[0];
        invs[wv * 32 + 16 + lane] = 1.0f / rs[1];
    }
    __syncthreads();
    for (int qj = 0; qj < 8; ++qj) {
        const float inv = invs[qj * 16 + l16];
        bf16x4 pk;
        for (int r = 0; r < 4; ++r) pk[r] = (bf16)(acc_o[qj][r] * inv);
        const int s = qt * 128 + qj * 16 + l16;
        *(bf16x4*)&CTX[(size_t)(b * SEQ + s) * DIMD + h * 64 + wv * 16 + quad * 4] = pk;
    }
}

// ---------------- output projection (unswapped; 64B-coalesced fp32 stores) ----------------
__global__ __launch_bounds__(256, 3) void oproj_kernel(
    const bf16* __restrict__ ctx, const bf16* __restrict__ wo,
    const float* __restrict__ bo, float* __restrict__ out) {
    __shared__ __align__(16) bf16 smem[2 * 128 * 64];
    const int tid = threadIdx.x;
    const int lane = tid & 63, wv = tid >> 6;
    const int quad = lane >> 4, l16 = lane & 15;
    const int wr = wv >> 1, wc = wv & 1;
    const int m0 = blockIdx.x * 128, n0 = blockIdx.y * 128;
    f32x4 acc[4][4] = {};
    gemm_core_768(ctx, wo, m0, n0, smem, smem + 128 * 64, acc);
    for (int ti = 0; ti < 4; ++ti) {
        const int rowb = m0 + wr * 64 + ti * 16 + quad * 4;
        for (int tj = 0; tj < 4; ++tj) {
            const int feat = n0 + wc * 64 + tj * 16 + l16;
            const float bv = bo[feat];
            for (int r = 0; r < 4; ++r)
                out[(size_t)(rowb + r) * DIMD + feat] = acc[ti][tj][r] + bv;
        }
    }
}

extern "C" void kernel_launch(void* const* d_in, const int* in_sizes, int n_in,
                              void* d_out, int out_size, void* d_ws, size_t ws_size,
                              hipStream_t stream) {
    const float* query = (const float*)d_in[0];
    const float* key_t = (const float*)d_in[1];
    const float* value = (const float*)d_in[2];
    const int*   mask  = (const int*)d_in[3];
    const float* q_w = (const float*)d_in[4];
    const float* q_b = (const float*)d_in[5];
    const float* k_w = (const float*)d_in[6];
    const float* k_b = (const float*)d_in[7];
    const float* v_w = (const float*)d_in[8];
    const float* v_b = (const float*)d_in[9];
    const float* o_w = (const float*)d_in[10];
    const float* o_b = (const float*)d_in[11];
    float* out = (float*)d_out;

    bf16* ws  = (bf16*)d_ws;
    bf16* W   = ws;                                  // 4 x WELEM
    bf16* XB  = ws + (size_t)4 * WELEM;              // bf16 X (reused per z); CTX aliases
    bf16* Qb  = XB + (size_t)MTOT * DIMD;            // [b][h][s][dh]
    bf16* Kb  = Qb + (size_t)MTOT * DIMD;            // [b][h][s][dh]
    bf16* Vb  = Kb + (size_t)MTOT * DIMD;            // [b][h][dh][s]
    bf16* CTX = XB;                                  // alias: XB dead after proj z=2

    convert_w_kernel<<<dim3(WELEM / 1024, 4), 256, 0, stream>>>(q_w, k_w, v_w, o_w, W);

    convert_x_kernel<<<MTOT * DIMD / 1024, 256, 0, stream>>>(query, XB);
    proj_kernel<<<dim3(64, 6), 256, 0, stream>>>(XB, W, q_b, Qb, 0);
    convert_x_kernel<<<MTOT * DIMD / 1024, 256, 0, stream>>>(key_t, XB);
    proj_kernel<<<dim3(64, 6), 256, 0, stream>>>(XB, W + (size_t)WELEM, k_b, Kb, 1);
    convert_x_kernel<<<MTOT * DIMD / 1024, 256, 0, stream>>>(value, XB);
    proj_kernel<<<dim3(64, 6), 256, 0, stream>>>(XB, W + (size_t)2 * WELEM, v_b, Vb, 2);

    attn_kernel<<<dim3(SEQ / 128, NHD, BSZ), 256, 0, stream>>>(Qb, Kb, Vb, mask, CTX);
    oproj_kernel<<<dim3(64, 6), 256, 0, stream>>>(CTX, W + (size_t)3 * WELEM, o_b, out);
}